// Round 1
// baseline (55569.220 us; speedup 1.0000x reference)
//
#include <hip/hip_runtime.h>
#include <hip/hip_cooperative_groups.h>
#include <cmath>

namespace cg = cooperative_groups;

constexpr int kB = 64;      // batch
constexpr int kS = 512;     // seq len
constexpr int kD = 128;     // input dim
constexpr int kH = 512;     // hidden dim
constexpr int kOut = 24;    // output dim
constexpr int kBlocks = 256;
constexpr int kThreads = 256;

struct Params {
  const float* x;
  const float* w0[4];   // f,i,o,g  each [512,640]
  const float* b0[4];
  const float* w1[4];   // f,i,o,g  each [512,1024]
  const float* b1[4];
  const float* fc1w; const float* fc1b;
  const float* fc2w; const float* fc2b;
  float* h0;    // 2 buffers [64][512] (double-buffered)
  float* h1;    // 2 buffers [64][512]
  float* tmp1;  // [64][512]
  float* out;   // [64][24]
};

__device__ __forceinline__ float sigmoidf_(float v) {
  return 1.0f / (1.0f + expf(-v));
}

// Persistent cooperative LSTM kernel.
// Block bid owns hidden columns j0=2*bid, j0+1 for all 4 gates, both layers.
// Thread decomposition for the GEMM phases: tid = kt*32 + rg*8 + bg
//   kt (0..7):  8-way k-split
//   rg (0..3):  gate index (0=f,1=i,2=o,3=g), thread covers both jl=0,1 rows
//   bg (0..7):  batch group (8 batches each)
__global__ void __launch_bounds__(kThreads, 1)
lstm_persistent(Params p) {
  cg::grid_group grid = cg::this_grid();

  __shared__ float u_stage[64 * 132];   // [b][k_local], 128 + 4 pad (bank-conflict-free)
  __shared__ float part[8 * 8 * 64];    // [kt][r][b] partial sums
  __shared__ float gates_s[8 * 64];     // [r][b] reduced gate preactivations

  const int tid = threadIdx.x;
  const int bid = blockIdx.x;
  const int kt = tid >> 5;
  const int rg = (tid >> 3) & 3;
  const int bg = tid & 7;
  const int j0 = bid * 2;

  // cell state lives in registers of threads 0..127 for the whole sequence
  float c0 = 0.f, c1 = 0.f;

  // zero-init h double-buffers (buffer 0 is read at t=0)
  if (tid < 128) {
    const int jl = tid >> 6, b = tid & 63;
    p.h0[b * kH + j0 + jl] = 0.f;
    p.h1[b * kH + j0 + jl] = 0.f;
  }
  grid.sync();

  for (int t = 0; t < kS; ++t) {
    const float* __restrict__ h0r = p.h0 + (t & 1) * (kB * kH);
    float* __restrict__ h0w = p.h0 + ((t + 1) & 1) * (kB * kH);
    const float* __restrict__ h1r = p.h1 + (t & 1) * (kB * kH);
    float* __restrict__ h1w = p.h1 + ((t + 1) & 1) * (kB * kH);

    // ================= phase A: layer 0, K = 640 (x:128 | h0:512) ============
    {
      float acc0[8], acc1[8];
      #pragma unroll
      for (int i = 0; i < 8; ++i) { acc0[i] = 0.f; acc1[i] = 0.f; }
      const float* __restrict__ wr0 = p.w0[rg] + j0 * 640;
      const float* __restrict__ wr1 = wr0 + 640;

      for (int c = 0; c < 5; ++c) {
        // stage u chunk [64 x 128] into LDS (coalesced float4)
        #pragma unroll
        for (int i = 0; i < 8; ++i) {
          const int f4id = tid + kThreads * i;
          const int b = f4id >> 5, k4 = f4id & 31;
          const int k = c * 128 + k4 * 4;
          float4 v;
          if (c == 0) {
            v = *(const float4*)(p.x + (b * kS + t) * kD + k);      // k < 128
          } else {
            v = *(const float4*)(h0r + b * kH + (k - 128));
          }
          *(float4*)(u_stage + b * 132 + k4 * 4) = v;
        }
        __syncthreads();
        #pragma unroll
        for (int m = 0; m < 4; ++m) {
          const int kl = kt * 16 + m * 4;
          const float4 w0v = *(const float4*)(wr0 + c * 128 + kl);
          const float4 w1v = *(const float4*)(wr1 + c * 128 + kl);
          #pragma unroll
          for (int i = 0; i < 8; ++i) {
            const int b = bg * 8 + i;
            const float4 uv = *(const float4*)(u_stage + b * 132 + kl);
            acc0[i] += w0v.x * uv.x + w0v.y * uv.y + w0v.z * uv.z + w0v.w * uv.w;
            acc1[i] += w1v.x * uv.x + w1v.y * uv.y + w1v.z * uv.z + w1v.w * uv.w;
          }
        }
        __syncthreads();
      }
      // write k-split partials
      {
        const int base0 = (kt * 8 + rg * 2) * 64 + bg * 8;
        const int base1 = (kt * 8 + rg * 2 + 1) * 64 + bg * 8;
        *(float4*)(part + base0)     = make_float4(acc0[0], acc0[1], acc0[2], acc0[3]);
        *(float4*)(part + base0 + 4) = make_float4(acc0[4], acc0[5], acc0[6], acc0[7]);
        *(float4*)(part + base1)     = make_float4(acc1[0], acc1[1], acc1[2], acc1[3]);
        *(float4*)(part + base1 + 4) = make_float4(acc1[4], acc1[5], acc1[6], acc1[7]);
      }
      __syncthreads();
      // reduce across kt + bias
      for (int o = tid; o < 512; o += kThreads) {
        const int r = o >> 6, b = o & 63;
        float s = 0.f;
        #pragma unroll
        for (int q = 0; q < 8; ++q) s += part[(q * 8 + r) * 64 + b];
        s += p.b0[r >> 1][j0 + (r & 1)];
        gates_s[r * 64 + b] = s;
      }
      __syncthreads();
      // cell update (threads 0..127 hold c0 state)
      if (tid < 128) {
        const int jl = tid >> 6, b = tid & 63;
        const float fg = sigmoidf_(gates_s[(0 + jl) * 64 + b]);
        const float ig = sigmoidf_(gates_s[(2 + jl) * 64 + b]);
        const float og = sigmoidf_(gates_s[(4 + jl) * 64 + b]);
        const float gg = tanhf(gates_s[(6 + jl) * 64 + b]);
        c0 = fg * c0 + ig * gg;
        h0w[b * kH + j0 + jl] = og * tanhf(c0);
      }
    }
    grid.sync();

    // ================= phase B: layer 1, K = 1024 (h0_new:512 | h1:512) ======
    {
      float acc0[8], acc1[8];
      #pragma unroll
      for (int i = 0; i < 8; ++i) { acc0[i] = 0.f; acc1[i] = 0.f; }
      const float* __restrict__ wr0 = p.w1[rg] + j0 * 1024;
      const float* __restrict__ wr1 = wr0 + 1024;

      for (int c = 0; c < 8; ++c) {
        #pragma unroll
        for (int i = 0; i < 8; ++i) {
          const int f4id = tid + kThreads * i;
          const int b = f4id >> 5, k4 = f4id & 31;
          const int k = c * 128 + k4 * 4;
          float4 v;
          if (k < 512) {
            v = *(const float4*)(h0w + b * kH + k);        // layer-0 output (new)
          } else {
            v = *(const float4*)(h1r + b * kH + (k - 512));
          }
          *(float4*)(u_stage + b * 132 + k4 * 4) = v;
        }
        __syncthreads();
        #pragma unroll
        for (int m = 0; m < 4; ++m) {
          const int kl = kt * 16 + m * 4;
          const float4 w0v = *(const float4*)(wr0 + c * 128 + kl);
          const float4 w1v = *(const float4*)(wr1 + c * 128 + kl);
          #pragma unroll
          for (int i = 0; i < 8; ++i) {
            const int b = bg * 8 + i;
            const float4 uv = *(const float4*)(u_stage + b * 132 + kl);
            acc0[i] += w0v.x * uv.x + w0v.y * uv.y + w0v.z * uv.z + w0v.w * uv.w;
            acc1[i] += w1v.x * uv.x + w1v.y * uv.y + w1v.z * uv.z + w1v.w * uv.w;
          }
        }
        __syncthreads();
      }
      {
        const int base0 = (kt * 8 + rg * 2) * 64 + bg * 8;
        const int base1 = (kt * 8 + rg * 2 + 1) * 64 + bg * 8;
        *(float4*)(part + base0)     = make_float4(acc0[0], acc0[1], acc0[2], acc0[3]);
        *(float4*)(part + base0 + 4) = make_float4(acc0[4], acc0[5], acc0[6], acc0[7]);
        *(float4*)(part + base1)     = make_float4(acc1[0], acc1[1], acc1[2], acc1[3]);
        *(float4*)(part + base1 + 4) = make_float4(acc1[4], acc1[5], acc1[6], acc1[7]);
      }
      __syncthreads();
      for (int o = tid; o < 512; o += kThreads) {
        const int r = o >> 6, b = o & 63;
        float s = 0.f;
        #pragma unroll
        for (int q = 0; q < 8; ++q) s += part[(q * 8 + r) * 64 + b];
        s += p.b1[r >> 1][j0 + (r & 1)];
        gates_s[r * 64 + b] = s;
      }
      __syncthreads();
      if (tid < 128) {
        const int jl = tid >> 6, b = tid & 63;
        const float fg = sigmoidf_(gates_s[(0 + jl) * 64 + b]);
        const float ig = sigmoidf_(gates_s[(2 + jl) * 64 + b]);
        const float og = sigmoidf_(gates_s[(4 + jl) * 64 + b]);
        const float gg = tanhf(gates_s[(6 + jl) * 64 + b]);
        c1 = fg * c1 + ig * gg;
        h1w[b * kH + j0 + jl] = og * tanhf(c1);
      }
    }
    grid.sync();
  }

  // ===== head: fc1 (linear) -> fc2 (linear) -> relu =====
  // final h1 is in buffer 0 (kS even). Each block computes its 2 fc1 columns.
  if (tid < 128) {
    const int jl = tid >> 6, b = tid & 63;
    const float* __restrict__ wr = p.fc1w + (j0 + jl) * kH;
    const float* __restrict__ hr = p.h1 + b * kH;
    float s = p.fc1b[j0 + jl];
    for (int k = 0; k < kH; k += 4) {
      const float4 wv = *(const float4*)(wr + k);
      const float4 hv = *(const float4*)(hr + k);
      s += wv.x * hv.x + wv.y * hv.y + wv.z * hv.z + wv.w * hv.w;
    }
    p.tmp1[b * kH + j0 + jl] = s;
  }
  grid.sync();
  if (bid < kOut && tid < kB) {
    const int b = tid;
    const float* __restrict__ wr = p.fc2w + bid * kH;
    const float* __restrict__ tr = p.tmp1 + b * kH;
    float s = p.fc2b[bid];
    for (int k = 0; k < kH; k += 4) {
      const float4 wv = *(const float4*)(wr + k);
      const float4 tv = *(const float4*)(tr + k);
      s += wv.x * tv.x + wv.y * tv.y + wv.z * tv.z + wv.w * tv.w;
    }
    p.out[b * kOut + bid] = fmaxf(s, 0.f);
  }
}

extern "C" void kernel_launch(void* const* d_in, const int* in_sizes, int n_in,
                              void* d_out, int out_size, void* d_ws, size_t ws_size,
                              hipStream_t stream) {
  (void)in_sizes; (void)n_in; (void)out_size; (void)ws_size;
  Params p;
  p.x = (const float*)d_in[0];
  // setup_inputs order: wf0,bf0,wi0,bi0,wo0,bo0,wg0,bg0, wf1,bf1,wi1,bi1,wo1,bo1,wg1,bg1
  p.w0[0] = (const float*)d_in[1];  p.b0[0] = (const float*)d_in[2];   // f
  p.w0[1] = (const float*)d_in[3];  p.b0[1] = (const float*)d_in[4];   // i
  p.w0[2] = (const float*)d_in[5];  p.b0[2] = (const float*)d_in[6];   // o
  p.w0[3] = (const float*)d_in[7];  p.b0[3] = (const float*)d_in[8];   // g
  p.w1[0] = (const float*)d_in[9];  p.b1[0] = (const float*)d_in[10];
  p.w1[1] = (const float*)d_in[11]; p.b1[1] = (const float*)d_in[12];
  p.w1[2] = (const float*)d_in[13]; p.b1[2] = (const float*)d_in[14];
  p.w1[3] = (const float*)d_in[15]; p.b1[3] = (const float*)d_in[16];
  p.fc1w = (const float*)d_in[17];  p.fc1b = (const float*)d_in[18];
  p.fc2w = (const float*)d_in[19];  p.fc2b = (const float*)d_in[20];

  float* ws = (float*)d_ws;
  p.h0   = ws;                       // 2 * 64*512 floats
  p.h1   = ws + 2 * kB * kH;         // 2 * 64*512 floats
  p.tmp1 = ws + 4 * kB * kH;         // 64*512 floats
  p.out  = (float*)d_out;

  void* args[] = { &p };
  hipLaunchCooperativeKernel(reinterpret_cast<const void*>(&lstm_persistent),
                             dim3(kBlocks), dim3(kThreads), args, 0, stream);
}

// Round 3
// 24828.088 us; speedup vs baseline: 2.2382x; 2.2382x over previous
//
#include <hip/hip_runtime.h>
#include <hip/hip_cooperative_groups.h>
#include <cmath>

namespace cg = cooperative_groups;

constexpr int kB = 64, kS = 512, kD = 128, kH = 512, kOut = 24;
constexpr int kBlocks = 256, kThreads = 512;   // grid<=256: proven coop-launchable

struct Params {
  const float* x;
  const float* w0[4]; const float* b0[4];   // f,i,o,g  [512,640] / [512]
  const float* w1[4]; const float* b1[4];   // f,i,o,g  [512,1024] / [512]
  const float* fc1w; const float* fc1b;
  const float* fc2w; const float* fc2b;
  float* H0;    // 2 buffers [64][512]
  float* H1;    // 2 buffers [64][512]
  float* tmp1;  // [64][512]
  float* out;   // [64][24]
};

__device__ __forceinline__ float sigmoidf_(float v) {
  return 1.0f / (1.0f + expf(-v));
}

// Block (cgi, bh): cgi=bid>>1 owns hidden cols j0=4*cgi..j0+3 (all 4 gates,
// 16 gate-rows), bh=bid&1 owns batches bh*32..bh*32+31.
// Thread tid = r4*128 + kt*8 + bg:
//   r4 (0..3): gate; thread covers that gate's 4 columns (rows r4*4+rr)
//   kt (0..15): k-split; within a 128-wide chunk thread owns f4 m*16+kt
//   bg (0..7): batches {bg, bg+8, bg+16, bg+24}
// LDS access patterns verified conflict-free: u-read bank quad = 4*(bg+k4)
// mod 32 distinct across the 8-lane group; partial stride 520 == 8 mod 32
// -> 2-way max (free).
__global__ void __launch_bounds__(kThreads, 2)
lstm_persistent(Params p) {
  cg::grid_group grid = cg::this_grid();

  __shared__ float ub[8320];   // union: u-stage 32x132 (4224) | partials 16x520
  __shared__ float gs[512];    // gate preactivations [row(16)][b_local(32)]

  const int tid = threadIdx.x;
  const int bid = blockIdx.x;
  const int cgi = bid >> 1;
  const int bh  = bid & 1;
  const int j0  = cgi * 4;
  const int bbase = bh * 32;

  const int r4 = tid >> 7;
  const int kt = (tid >> 3) & 15;
  const int bg = tid & 7;

  // zero-init buffers read at t=0 (buffer index 1)
  if (tid < 128) {
    const int jl = tid >> 5, bb = tid & 31;
    const int b = bbase + bb;
    p.H0[kB * kH + b * kH + j0 + jl] = 0.f;
    p.H1[kB * kH + b * kH + j0 + jl] = 0.f;
  }

  float* H0buf[2] = { p.H0, p.H0 + kB * kH };
  float* H1buf[2] = { p.H1, p.H1 + kB * kH };
  float c0 = 0.f, c1 = 0.f;

  grid.sync();

  // ---------- layer 0: u = [x_t (128) | h0_prev (512)], K=640 ----------
  auto phaseA = [&](int t, const float* __restrict__ h0prev,
                    float* __restrict__ h0out) {
    float acc[4][4];
    #pragma unroll
    for (int a = 0; a < 4; ++a)
      #pragma unroll
      for (int q = 0; q < 4; ++q) acc[a][q] = 0.f;

    const float* wrow[4];
    #pragma unroll
    for (int rr = 0; rr < 4; ++rr)
      wrow[rr] = p.w0[r4] + (j0 + rr) * 640;

    for (int c = 0; c < 5; ++c) {
      #pragma unroll
      for (int i2 = 0; i2 < 2; ++i2) {
        const int f4 = tid + kThreads * i2;
        const int k4s = f4 & 31, bbs = f4 >> 5;
        const int b = bbase + bbs;
        const float4 v = (c == 0)
          ? *(const float4*)(p.x + (b * kS + t) * kD + k4s * 4)
          : *(const float4*)(h0prev + b * kH + (c - 1) * 128 + k4s * 4);
        *(float4*)(ub + bbs * 132 + k4s * 4) = v;
      }
      __syncthreads();
      #pragma unroll
      for (int m = 0; m < 2; ++m) {
        const int k4 = m * 16 + kt;
        float4 wv[4], uv[4];
        #pragma unroll
        for (int rr = 0; rr < 4; ++rr)
          wv[rr] = *(const float4*)(wrow[rr] + c * 128 + k4 * 4);
        #pragma unroll
        for (int i2 = 0; i2 < 4; ++i2)
          uv[i2] = *(const float4*)(ub + (bg + 8 * i2) * 132 + k4 * 4);
        #pragma unroll
        for (int rr = 0; rr < 4; ++rr)
          #pragma unroll
          for (int i2 = 0; i2 < 4; ++i2) {
            acc[rr][i2] = fmaf(wv[rr].x, uv[i2].x, acc[rr][i2]);
            acc[rr][i2] = fmaf(wv[rr].y, uv[i2].y, acc[rr][i2]);
            acc[rr][i2] = fmaf(wv[rr].z, uv[i2].z, acc[rr][i2]);
            acc[rr][i2] = fmaf(wv[rr].w, uv[i2].w, acc[rr][i2]);
          }
      }
      __syncthreads();
    }
    #pragma unroll
    for (int rr = 0; rr < 4; ++rr)
      #pragma unroll
      for (int i2 = 0; i2 < 4; ++i2)
        ub[kt * 520 + (r4 * 4 + rr) * 32 + bg + 8 * i2] = acc[rr][i2];
    __syncthreads();
    {
      const int row = tid >> 5;
      float s = 0.f;
      #pragma unroll
      for (int q = 0; q < 16; ++q) s += ub[q * 520 + tid];
      s += p.b0[row >> 2][j0 + (row & 3)];
      gs[tid] = s;
    }
    __syncthreads();
    if (tid < 128) {
      const int jl = tid >> 5, bb = tid & 31;
      const int b = bbase + bb;
      const float fg = sigmoidf_(gs[(0 + jl) * 32 + bb]);
      const float ig = sigmoidf_(gs[(4 + jl) * 32 + bb]);
      const float og = sigmoidf_(gs[(8 + jl) * 32 + bb]);
      const float gg = tanhf(gs[(12 + jl) * 32 + bb]);
      c0 = fg * c0 + ig * gg;
      h0out[b * kH + j0 + jl] = og * tanhf(c0);
    }
  };

  // ---------- layer 1: u = [h0_cur (512) | h1_prev (512)], K=1024 ----------
  auto phaseB = [&](const float* __restrict__ h0cur,
                    const float* __restrict__ h1prev,
                    float* __restrict__ h1out) {
    float acc[4][4];
    #pragma unroll
    for (int a = 0; a < 4; ++a)
      #pragma unroll
      for (int q = 0; q < 4; ++q) acc[a][q] = 0.f;

    const float* wrow[4];
    #pragma unroll
    for (int rr = 0; rr < 4; ++rr)
      wrow[rr] = p.w1[r4] + (j0 + rr) * 1024;

    for (int c = 0; c < 8; ++c) {
      #pragma unroll
      for (int i2 = 0; i2 < 2; ++i2) {
        const int f4 = tid + kThreads * i2;
        const int k4s = f4 & 31, bbs = f4 >> 5;
        const int b = bbase + bbs;
        const float4 v = (c < 4)
          ? *(const float4*)(h0cur + b * kH + c * 128 + k4s * 4)
          : *(const float4*)(h1prev + b * kH + (c - 4) * 128 + k4s * 4);
        *(float4*)(ub + bbs * 132 + k4s * 4) = v;
      }
      __syncthreads();
      #pragma unroll
      for (int m = 0; m < 2; ++m) {
        const int k4 = m * 16 + kt;
        float4 wv[4], uv[4];
        #pragma unroll
        for (int rr = 0; rr < 4; ++rr)
          wv[rr] = *(const float4*)(wrow[rr] + c * 128 + k4 * 4);
        #pragma unroll
        for (int i2 = 0; i2 < 4; ++i2)
          uv[i2] = *(const float4*)(ub + (bg + 8 * i2) * 132 + k4 * 4);
        #pragma unroll
        for (int rr = 0; rr < 4; ++rr)
          #pragma unroll
          for (int i2 = 0; i2 < 4; ++i2) {
            acc[rr][i2] = fmaf(wv[rr].x, uv[i2].x, acc[rr][i2]);
            acc[rr][i2] = fmaf(wv[rr].y, uv[i2].y, acc[rr][i2]);
            acc[rr][i2] = fmaf(wv[rr].z, uv[i2].z, acc[rr][i2]);
            acc[rr][i2] = fmaf(wv[rr].w, uv[i2].w, acc[rr][i2]);
          }
      }
      __syncthreads();
    }
    #pragma unroll
    for (int rr = 0; rr < 4; ++rr)
      #pragma unroll
      for (int i2 = 0; i2 < 4; ++i2)
        ub[kt * 520 + (r4 * 4 + rr) * 32 + bg + 8 * i2] = acc[rr][i2];
    __syncthreads();
    {
      const int row = tid >> 5;
      float s = 0.f;
      #pragma unroll
      for (int q = 0; q < 16; ++q) s += ub[q * 520 + tid];
      s += p.b1[row >> 2][j0 + (row & 3)];
      gs[tid] = s;
    }
    __syncthreads();
    if (tid < 128) {
      const int jl = tid >> 5, bb = tid & 31;
      const int b = bbase + bb;
      const float fg = sigmoidf_(gs[(0 + jl) * 32 + bb]);
      const float ig = sigmoidf_(gs[(4 + jl) * 32 + bb]);
      const float og = sigmoidf_(gs[(8 + jl) * 32 + bb]);
      const float gg = tanhf(gs[(12 + jl) * 32 + bb]);
      c1 = fg * c1 + ig * gg;
      h1out[b * kH + j0 + jl] = og * tanhf(c1);
    }
  };

  // ---------- fused sequence: 1 grid sync per step ----------
  // Round t = { phaseB(t); phaseA(t+1); grid.sync }. All cross-block RAW/WAR
  // pairs are separated by >=1 grid.sync (B reads h0(t)/h1(t-1) synced in the
  // previous round; A(t+1) writes the buffer B(t) is NOT reading).
  phaseA(0, H0buf[1], H0buf[0]);
  grid.sync();
  for (int t = 0; t < kS; ++t) {
    phaseB(H0buf[t & 1], H1buf[(t + 1) & 1], H1buf[t & 1]);
    if (t < kS - 1) phaseA(t + 1, H0buf[t & 1], H0buf[(t + 1) & 1]);
    grid.sync();
  }

  // ---------- head: fc1 -> fc2 -> relu ----------
  const float* h1f = H1buf[(kS - 1) & 1];
  if (tid < 128) {
    const int jl = tid >> 5, bb = tid & 31;
    const int b = bbase + bb;
    const float* __restrict__ wr = p.fc1w + (j0 + jl) * kH;
    const float* __restrict__ hr = h1f + b * kH;
    float s = p.fc1b[j0 + jl];
    for (int k = 0; k < kH; k += 4) {
      const float4 wv = *(const float4*)(wr + k);
      const float4 hv = *(const float4*)(hr + k);
      s = fmaf(wv.x, hv.x, s); s = fmaf(wv.y, hv.y, s);
      s = fmaf(wv.z, hv.z, s); s = fmaf(wv.w, hv.w, s);
    }
    p.tmp1[b * kH + j0 + jl] = s;
  }
  grid.sync();
  if (bid < kOut && tid < kB) {
    const int b = tid;
    const float* __restrict__ wr = p.fc2w + bid * kH;
    const float* __restrict__ tr = p.tmp1 + b * kH;
    float s = p.fc2b[bid];
    for (int k = 0; k < kH; k += 4) {
      const float4 wv = *(const float4*)(wr + k);
      const float4 tv = *(const float4*)(tr + k);
      s = fmaf(wv.x, tv.x, s); s = fmaf(wv.y, tv.y, s);
      s = fmaf(wv.z, tv.z, s); s = fmaf(wv.w, tv.w, s);
    }
    p.out[b * kOut + bid] = fmaxf(s, 0.f);
  }
}

extern "C" void kernel_launch(void* const* d_in, const int* in_sizes, int n_in,
                              void* d_out, int out_size, void* d_ws, size_t ws_size,
                              hipStream_t stream) {
  (void)in_sizes; (void)n_in; (void)out_size; (void)ws_size;
  Params p;
  p.x = (const float*)d_in[0];
  p.w0[0] = (const float*)d_in[1];  p.b0[0] = (const float*)d_in[2];
  p.w0[1] = (const float*)d_in[3];  p.b0[1] = (const float*)d_in[4];
  p.w0[2] = (const float*)d_in[5];  p.b0[2] = (const float*)d_in[6];
  p.w0[3] = (const float*)d_in[7];  p.b0[3] = (const float*)d_in[8];
  p.w1[0] = (const float*)d_in[9];  p.b1[0] = (const float*)d_in[10];
  p.w1[1] = (const float*)d_in[11]; p.b1[1] = (const float*)d_in[12];
  p.w1[2] = (const float*)d_in[13]; p.b1[2] = (const float*)d_in[14];
  p.w1[3] = (const float*)d_in[15]; p.b1[3] = (const float*)d_in[16];
  p.fc1w = (const float*)d_in[17];  p.fc1b = (const float*)d_in[18];
  p.fc2w = (const float*)d_in[19];  p.fc2b = (const float*)d_in[20];

  float* ws = (float*)d_ws;
  p.H0   = ws;                       // 2 * 64*512
  p.H1   = ws + 2 * kB * kH;         // 2 * 64*512
  p.tmp1 = ws + 4 * kB * kH;         // 64*512
  p.out  = (float*)d_out;

  void* args[] = { &p };
  hipLaunchCooperativeKernel(reinterpret_cast<const void*>(&lstm_persistent),
                             dim3(kBlocks), dim3(kThreads), args, 0, stream);
}

// Round 4
// 17634.830 us; speedup vs baseline: 3.1511x; 1.4079x over previous
//
#include <hip/hip_runtime.h>
#include <cmath>

constexpr int kB = 64, kS = 512, kD = 128, kH = 512, kOut = 24;
constexpr int kBlocks = 256, kThreads = 512;   // grid<=256: proven coop-launchable
constexpr size_t kBarOffBytes = (size_t)5 * kB * kH * 4;   // after H0,H1,tmp1

struct Params {
  const float* x;
  const float* w0[4]; const float* b0[4];   // f,i,o,g  [512,640] / [512]
  const float* w1[4]; const float* b1[4];   // f,i,o,g  [512,1024] / [512]
  const float* fc1w; const float* fc1b;
  const float* fc2w; const float* fc2b;
  float* H0;    // 2 buffers [64][512]
  float* H1;    // 2 buffers [64][512]
  float* tmp1;  // [64][512]
  unsigned* bar; // barrier state: leaf[8] @ i*16, root @ 128, gen @ 144
  float* out;   // [64][24]
};

__device__ __forceinline__ float sigmoidf_(float v) {
  return 1.0f / (1.0f + expf(-v));
}

// Two-level monotone barrier. Leaf = bid&7 (one per XCD under round-robin
// dispatch; perf-only assumption). 32 blocks/leaf, 8 leaves -> root -> gen.
// Fence+relaxed-RMW on arrive, RMW-read+fence at each winner hop: fence-to-
// fence release/acquire chains give grid-wide happens-before. Monotone
// counters (target depends on round r) -> no reset race. s_sleep spin.
__device__ __forceinline__ void grid_barrier(unsigned* bar, int bid, unsigned r) {
  __syncthreads();
  if (threadIdx.x == 0) {
    __threadfence();                                  // release
    unsigned prev = atomicAdd(&bar[(bid & 7) * 16], 1u);
    if (prev == r * 32u + 31u) {                      // leaf winner
      __threadfence();
      unsigned rp = atomicAdd(&bar[128], 1u);
      if (rp == r * 8u + 7u) {                        // root winner
        __threadfence();
        atomicAdd(&bar[144], 1u);                     // gen = r+1
      }
    }
    while (__hip_atomic_load(&bar[144], __ATOMIC_RELAXED,
                             __HIP_MEMORY_SCOPE_AGENT) <= r) {
      __builtin_amdgcn_s_sleep(2);
    }
    __threadfence();                                  // acquire
  }
  __syncthreads();
}

// Block (cgi, bh): cgi=bid>>1 owns hidden cols j0=4*cgi..j0+3 (all 4 gates,
// 16 gate-rows), bh=bid&1 owns batches bh*32..bh*32+31.
// Thread tid = r4*128 + kt*8 + bg  (r4: gate, kt: k-split, bg: batch group).
__global__ void __launch_bounds__(kThreads, 2)
lstm_persistent(Params p) {
  __shared__ float ub[8320];   // union: u-stage 32x132 (4224) | partials 16x520
  __shared__ float gs[512];    // gate preactivations [row(16)][b_local(32)]

  const int tid = threadIdx.x;
  const int bid = blockIdx.x;
  const int cgi = bid >> 1;
  const int bh  = bid & 1;
  const int j0  = cgi * 4;
  const int bbase = bh * 32;

  const int r4 = tid >> 7;
  const int kt = (tid >> 3) & 15;
  const int bg = tid & 7;

  unsigned rnd = 0;

  // zero-init buffers read at t=0 (buffer index 1)
  if (tid < 128) {
    const int jl = tid >> 5, bb = tid & 31;
    const int b = bbase + bb;
    p.H0[kB * kH + b * kH + j0 + jl] = 0.f;
    p.H1[kB * kH + b * kH + j0 + jl] = 0.f;
  }

  float* H0buf[2] = { p.H0, p.H0 + kB * kH };
  float* H1buf[2] = { p.H1, p.H1 + kB * kH };
  float c0 = 0.f, c1 = 0.f;

  grid_barrier(p.bar, bid, rnd++);

  // ---------- layer 0: u = [x_t (128) | h0_prev (512)], K=640 ----------
  auto phaseA = [&](int t, const float* __restrict__ h0prev,
                    float* __restrict__ h0out) {
    float acc[4][4];
    #pragma unroll
    for (int a = 0; a < 4; ++a)
      #pragma unroll
      for (int q = 0; q < 4; ++q) acc[a][q] = 0.f;

    const float* wrow[4];
    #pragma unroll
    for (int rr = 0; rr < 4; ++rr)
      wrow[rr] = p.w0[r4] + (j0 + rr) * 640;

    for (int c = 0; c < 5; ++c) {
      #pragma unroll
      for (int i2 = 0; i2 < 2; ++i2) {
        const int f4 = tid + kThreads * i2;
        const int k4s = f4 & 31, bbs = f4 >> 5;
        const int b = bbase + bbs;
        const float4 v = (c == 0)
          ? *(const float4*)(p.x + (b * kS + t) * kD + k4s * 4)
          : *(const float4*)(h0prev + b * kH + (c - 1) * 128 + k4s * 4);
        *(float4*)(ub + bbs * 132 + k4s * 4) = v;
      }
      __syncthreads();
      #pragma unroll
      for (int m = 0; m < 2; ++m) {
        const int k4 = m * 16 + kt;
        float4 wv[4], uv[4];
        #pragma unroll
        for (int rr = 0; rr < 4; ++rr)
          wv[rr] = *(const float4*)(wrow[rr] + c * 128 + k4 * 4);
        #pragma unroll
        for (int i2 = 0; i2 < 4; ++i2)
          uv[i2] = *(const float4*)(ub + (bg + 8 * i2) * 132 + k4 * 4);
        #pragma unroll
        for (int rr = 0; rr < 4; ++rr)
          #pragma unroll
          for (int i2 = 0; i2 < 4; ++i2) {
            acc[rr][i2] = fmaf(wv[rr].x, uv[i2].x, acc[rr][i2]);
            acc[rr][i2] = fmaf(wv[rr].y, uv[i2].y, acc[rr][i2]);
            acc[rr][i2] = fmaf(wv[rr].z, uv[i2].z, acc[rr][i2]);
            acc[rr][i2] = fmaf(wv[rr].w, uv[i2].w, acc[rr][i2]);
          }
      }
      __syncthreads();
    }
    #pragma unroll
    for (int rr = 0; rr < 4; ++rr)
      #pragma unroll
      for (int i2 = 0; i2 < 4; ++i2)
        ub[kt * 520 + (r4 * 4 + rr) * 32 + bg + 8 * i2] = acc[rr][i2];
    __syncthreads();
    {
      const int row = tid >> 5;
      float s = 0.f;
      #pragma unroll
      for (int q = 0; q < 16; ++q) s += ub[q * 520 + tid];
      s += p.b0[row >> 2][j0 + (row & 3)];
      gs[tid] = s;
    }
    __syncthreads();
    if (tid < 128) {
      const int jl = tid >> 5, bb = tid & 31;
      const int b = bbase + bb;
      const float fg = sigmoidf_(gs[(0 + jl) * 32 + bb]);
      const float ig = sigmoidf_(gs[(4 + jl) * 32 + bb]);
      const float og = sigmoidf_(gs[(8 + jl) * 32 + bb]);
      const float gg = tanhf(gs[(12 + jl) * 32 + bb]);
      c0 = fg * c0 + ig * gg;
      h0out[b * kH + j0 + jl] = og * tanhf(c0);
    }
  };

  // ---------- layer 1: u = [h0_cur (512) | h1_prev (512)], K=1024 ----------
  auto phaseB = [&](const float* __restrict__ h0cur,
                    const float* __restrict__ h1prev,
                    float* __restrict__ h1out) {
    float acc[4][4];
    #pragma unroll
    for (int a = 0; a < 4; ++a)
      #pragma unroll
      for (int q = 0; q < 4; ++q) acc[a][q] = 0.f;

    const float* wrow[4];
    #pragma unroll
    for (int rr = 0; rr < 4; ++rr)
      wrow[rr] = p.w1[r4] + (j0 + rr) * 1024;

    for (int c = 0; c < 8; ++c) {
      #pragma unroll
      for (int i2 = 0; i2 < 2; ++i2) {
        const int f4 = tid + kThreads * i2;
        const int k4s = f4 & 31, bbs = f4 >> 5;
        const int b = bbase + bbs;
        const float4 v = (c < 4)
          ? *(const float4*)(h0cur + b * kH + c * 128 + k4s * 4)
          : *(const float4*)(h1prev + b * kH + (c - 4) * 128 + k4s * 4);
        *(float4*)(ub + bbs * 132 + k4s * 4) = v;
      }
      __syncthreads();
      #pragma unroll
      for (int m = 0; m < 2; ++m) {
        const int k4 = m * 16 + kt;
        float4 wv[4], uv[4];
        #pragma unroll
        for (int rr = 0; rr < 4; ++rr)
          wv[rr] = *(const float4*)(wrow[rr] + c * 128 + k4 * 4);
        #pragma unroll
        for (int i2 = 0; i2 < 4; ++i2)
          uv[i2] = *(const float4*)(ub + (bg + 8 * i2) * 132 + k4 * 4);
        #pragma unroll
        for (int rr = 0; rr < 4; ++rr)
          #pragma unroll
          for (int i2 = 0; i2 < 4; ++i2) {
            acc[rr][i2] = fmaf(wv[rr].x, uv[i2].x, acc[rr][i2]);
            acc[rr][i2] = fmaf(wv[rr].y, uv[i2].y, acc[rr][i2]);
            acc[rr][i2] = fmaf(wv[rr].z, uv[i2].z, acc[rr][i2]);
            acc[rr][i2] = fmaf(wv[rr].w, uv[i2].w, acc[rr][i2]);
          }
      }
      __syncthreads();
    }
    #pragma unroll
    for (int rr = 0; rr < 4; ++rr)
      #pragma unroll
      for (int i2 = 0; i2 < 4; ++i2)
        ub[kt * 520 + (r4 * 4 + rr) * 32 + bg + 8 * i2] = acc[rr][i2];
    __syncthreads();
    {
      const int row = tid >> 5;
      float s = 0.f;
      #pragma unroll
      for (int q = 0; q < 16; ++q) s += ub[q * 520 + tid];
      s += p.b1[row >> 2][j0 + (row & 3)];
      gs[tid] = s;
    }
    __syncthreads();
    if (tid < 128) {
      const int jl = tid >> 5, bb = tid & 31;
      const int b = bbase + bb;
      const float fg = sigmoidf_(gs[(0 + jl) * 32 + bb]);
      const float ig = sigmoidf_(gs[(4 + jl) * 32 + bb]);
      const float og = sigmoidf_(gs[(8 + jl) * 32 + bb]);
      const float gg = tanhf(gs[(12 + jl) * 32 + bb]);
      c1 = fg * c1 + ig * gg;
      h1out[b * kH + j0 + jl] = og * tanhf(c1);
    }
  };

  // ---------- fused sequence: 1 barrier per step ----------
  phaseA(0, H0buf[1], H0buf[0]);
  grid_barrier(p.bar, bid, rnd++);
  for (int t = 0; t < kS; ++t) {
    phaseB(H0buf[t & 1], H1buf[(t + 1) & 1], H1buf[t & 1]);
    if (t < kS - 1) phaseA(t + 1, H0buf[t & 1], H0buf[(t + 1) & 1]);
    grid_barrier(p.bar, bid, rnd++);
  }

  // ---------- head: fc1 -> fc2 -> relu ----------
  const float* h1f = H1buf[(kS - 1) & 1];
  if (tid < 128) {
    const int jl = tid >> 5, bb = tid & 31;
    const int b = bbase + bb;
    const float* __restrict__ wr = p.fc1w + (j0 + jl) * kH;
    const float* __restrict__ hr = h1f + b * kH;
    float s = p.fc1b[j0 + jl];
    for (int k = 0; k < kH; k += 4) {
      const float4 wv = *(const float4*)(wr + k);
      const float4 hv = *(const float4*)(hr + k);
      s = fmaf(wv.x, hv.x, s); s = fmaf(wv.y, hv.y, s);
      s = fmaf(wv.z, hv.z, s); s = fmaf(wv.w, hv.w, s);
    }
    p.tmp1[b * kH + j0 + jl] = s;
  }
  grid_barrier(p.bar, bid, rnd++);
  if (bid < kOut && tid < kB) {
    const int b = tid;
    const float* __restrict__ wr = p.fc2w + bid * kH;
    const float* __restrict__ tr = p.tmp1 + b * kH;
    float s = p.fc2b[bid];
    for (int k = 0; k < kH; k += 4) {
      const float4 wv = *(const float4*)(wr + k);
      const float4 tv = *(const float4*)(tr + k);
      s = fmaf(wv.x, tv.x, s); s = fmaf(wv.y, tv.y, s);
      s = fmaf(wv.z, tv.z, s); s = fmaf(wv.w, tv.w, s);
    }
    p.out[b * kOut + bid] = fmaxf(s, 0.f);
  }
}

extern "C" void kernel_launch(void* const* d_in, const int* in_sizes, int n_in,
                              void* d_out, int out_size, void* d_ws, size_t ws_size,
                              hipStream_t stream) {
  (void)in_sizes; (void)n_in; (void)out_size; (void)ws_size;
  Params p;
  p.x = (const float*)d_in[0];
  p.w0[0] = (const float*)d_in[1];  p.b0[0] = (const float*)d_in[2];
  p.w0[1] = (const float*)d_in[3];  p.b0[1] = (const float*)d_in[4];
  p.w0[2] = (const float*)d_in[5];  p.b0[2] = (const float*)d_in[6];
  p.w0[3] = (const float*)d_in[7];  p.b0[3] = (const float*)d_in[8];
  p.w1[0] = (const float*)d_in[9];  p.b1[0] = (const float*)d_in[10];
  p.w1[1] = (const float*)d_in[11]; p.b1[1] = (const float*)d_in[12];
  p.w1[2] = (const float*)d_in[13]; p.b1[2] = (const float*)d_in[14];
  p.w1[3] = (const float*)d_in[15]; p.b1[3] = (const float*)d_in[16];
  p.fc1w = (const float*)d_in[17];  p.fc1b = (const float*)d_in[18];
  p.fc2w = (const float*)d_in[19];  p.fc2b = (const float*)d_in[20];

  float* ws = (float*)d_ws;
  p.H0   = ws;                       // 2 * 64*512
  p.H1   = ws + 2 * kB * kH;         // 2 * 64*512
  p.tmp1 = ws + 4 * kB * kH;         // 64*512
  p.bar  = (unsigned*)((char*)d_ws + kBarOffBytes);
  p.out  = (float*)d_out;

  // barrier counters must start at 0 (ws is poisoned 0xAA before every launch)
  hipMemsetAsync((char*)d_ws + kBarOffBytes, 0, 1024, stream);

  void* args[] = { &p };
  hipLaunchCooperativeKernel(reinterpret_cast<const void*>(&lstm_persistent),
                             dim3(kBlocks), dim3(kThreads), args, 0, stream);
}